// Round 1
// baseline (7218.198 us; speedup 1.0000x reference)
//
#include <hip/hip_runtime.h>
#include <math.h>

// LieNet: h = gelu(src @ map_w^T + map_b)            (S*B=131072 rows, D=256)
//         blacket(a,b) = gelu(a@W1^T + b@W2^T + bl_b) with W1=bl_w[:,:256], W2=bl_w[:,256:]
//         delta = x + blacket(x, h),  x = h shifted by -B rows (zero-fill)
//         J = blacket(a,bc) + blacket(b,ca) + blacket(c,ab) over 130560 rows
//         out = cumsum(delta.at[2:].add(J), axis=0)
//
// Round 1: correctness-first fp32 tiled GEMM (no fp32 MFMA on CDNA4).
// One generic blacket kernel; shifted views of h expressed via row offsets
// with zero-fill; J accumulated in-place into d_out; in-place cumsum.

#define DD 256
#define TM 64
#define TN 64
#define TK 16

__device__ __forceinline__ float gelu_exact(float v) {
    // jax.nn.gelu(approximate=False) = v * 0.5 * (1 + erf(v / sqrt(2)))
    return 0.5f * v * (1.0f + erff(v * 0.70710678118654752440f));
}

// out[n, j] (+)= gelu( sum_k A[n+a_shift, k] * W[j, woff0 + k]
//                    + sum_k Bv[n+b_shift, k] * W[j, woff1 + k] + bias[j] )
// Rows outside [0, rows) are treated as zero (handles the x-shift padding).
// mode 0: out = g;  mode 1: out = g + A[n+a_shift, j] (the "x + blacket" form);
// mode 2: out += g.
// npass==1: only the A/W-first-half product (used for the h projection).
__global__ __launch_bounds__(256) void blacket_kernel(
    const float* __restrict__ A, int a_shift, int a_rows,
    const float* __restrict__ Bv, int b_shift, int b_rows,
    const float* __restrict__ W, int w_stride, int npass,
    const float* __restrict__ bias,
    float* __restrict__ out, int nrows, int mode)
{
    __shared__ float As[TM][TK + 1];
    __shared__ float Ws[TN][TK + 1];

    const int tid = threadIdx.x;
    const int tx = tid & 15;        // 16 thread cols
    const int ty = tid >> 4;        // 16 thread rows
    const int bm = blockIdx.x * TM;
    const int bn = blockIdx.y * TN;

    float acc[4][4];
    #pragma unroll
    for (int i = 0; i < 4; ++i)
        #pragma unroll
        for (int j = 0; j < 4; ++j) acc[i][j] = 0.0f;

    for (int p = 0; p < npass; ++p) {
        const float* __restrict__ X = (p == 0) ? A : Bv;
        const int shift = (p == 0) ? a_shift : b_shift;
        const int xrows = (p == 0) ? a_rows : b_rows;
        const int woff = p * DD;

        for (int k0 = 0; k0 < DD; k0 += TK) {
            #pragma unroll
            for (int l = tid; l < TM * TK; l += 256) {
                const int r = l >> 4;
                const int c = l & 15;
                const int gr = bm + r + shift;
                As[r][c] = (gr >= 0 && gr < xrows) ? X[(long)gr * DD + k0 + c] : 0.0f;
                const int wr = bn + r;
                Ws[r][c] = W[(long)wr * w_stride + woff + k0 + c];
            }
            __syncthreads();

            #pragma unroll
            for (int kk = 0; kk < TK; ++kk) {
                float av[4], wv[4];
                #pragma unroll
                for (int i = 0; i < 4; ++i) av[i] = As[ty * 4 + i][kk];
                #pragma unroll
                for (int j = 0; j < 4; ++j) wv[j] = Ws[tx * 4 + j][kk];
                #pragma unroll
                for (int i = 0; i < 4; ++i)
                    #pragma unroll
                    for (int j = 0; j < 4; ++j)
                        acc[i][j] += av[i] * wv[j];
            }
            __syncthreads();
        }
    }

    #pragma unroll
    for (int i = 0; i < 4; ++i) {
        const int gm = bm + ty * 4 + i;
        if (gm >= nrows) continue;
        #pragma unroll
        for (int j = 0; j < 4; ++j) {
            const int gn = bn + tx * 4 + j;
            float g = gelu_exact(acc[i][j] + bias[gn]);
            if (mode == 1) {
                const int sr = gm + a_shift;
                const float xv = (sr >= 0 && sr < a_rows) ? A[(long)sr * DD + gn] : 0.0f;
                g += xv;
            }
            if (mode == 2) out[(long)gm * DD + gn] += g;
            else           out[(long)gm * DD + gn] = g;
        }
    }
}

// In-place cumsum along S: one thread per (b, d) position, 512 serial steps.
__global__ __launch_bounds__(256) void cumsum_kernel(float* __restrict__ out)
{
    const int idx = blockIdx.x * blockDim.x + threadIdx.x;   // 0 .. 65535
    float acc = 0.0f;
    for (int s = 0; s < 512; ++s) {
        const long off = (long)s * 65536 + idx;
        acc += out[off];
        out[off] = acc;
    }
}

extern "C" void kernel_launch(void* const* d_in, const int* in_sizes, int n_in,
                              void* d_out, int out_size, void* d_ws, size_t ws_size,
                              hipStream_t stream)
{
    const float* src   = (const float*)d_in[0];   // (512*256, 256)
    const float* map_w = (const float*)d_in[1];   // (256, 256)
    const float* map_b = (const float*)d_in[2];   // (256,)
    const float* bl_w  = (const float*)d_in[3];   // (256, 512)
    const float* bl_b  = (const float*)d_in[4];   // (256,)
    float* out = (float*)d_out;                   // (512*256, 256)

    const int SB = 512 * 256;        // 131072 rows
    const int NJ = 510 * 256;        // 130560 rows
    const int B  = 256;              // rows per S-step

    float* h   = (float*)d_ws;                    // 131072*256 floats = 128 MB
    float* tmp = h + (long)SB * DD;               // 130560*256 floats = 127.6 MB

    dim3 blk(256);
    dim3 grid_h((SB + TM - 1) / TM, DD / TN);
    dim3 grid_j((NJ + TM - 1) / TM, DD / TN);

    // 1. h = gelu(src @ map_w^T + map_b)   (single-operand pass)
    blacket_kernel<<<grid_h, blk, 0, stream>>>(src, 0, SB, nullptr, 0, 0,
                                               map_w, DD, 1, map_b, h, SB, 0);
    // 2. out = x + blacket(x, h);  x = h shifted by -B (zero-fill)
    blacket_kernel<<<grid_h, blk, 0, stream>>>(h, -B, SB, h, 0, SB,
                                               bl_w, 2 * DD, 2, bl_b, out, SB, 1);
    // 3. tmp = bc = blacket(h[+B], h[+2B])
    blacket_kernel<<<grid_j, blk, 0, stream>>>(h, B, SB, h, 2 * B, SB,
                                               bl_w, 2 * DD, 2, bl_b, tmp, NJ, 0);
    // 4. out[2B:] += blacket(h, bc)
    blacket_kernel<<<grid_j, blk, 0, stream>>>(h, 0, SB, tmp, 0, NJ,
                                               bl_w, 2 * DD, 2, bl_b, out + (long)2 * B * DD, NJ, 2);
    // 5. tmp = ca = blacket(h[+2B], h)
    blacket_kernel<<<grid_j, blk, 0, stream>>>(h, 2 * B, SB, h, 0, SB,
                                               bl_w, 2 * DD, 2, bl_b, tmp, NJ, 0);
    // 6. out[2B:] += blacket(h[+B], ca)
    blacket_kernel<<<grid_j, blk, 0, stream>>>(h, B, SB, tmp, 0, NJ,
                                               bl_w, 2 * DD, 2, bl_b, out + (long)2 * B * DD, NJ, 2);
    // 7. tmp = ab = blacket(h, h[+B])
    blacket_kernel<<<grid_j, blk, 0, stream>>>(h, 0, SB, h, B, SB,
                                               bl_w, 2 * DD, 2, bl_b, tmp, NJ, 0);
    // 8. out[2B:] += blacket(h[+2B], ab)
    blacket_kernel<<<grid_j, blk, 0, stream>>>(h, 2 * B, SB, tmp, 0, NJ,
                                               bl_w, 2 * DD, 2, bl_b, out + (long)2 * B * DD, NJ, 2);
    // 9. in-place cumsum along S
    cumsum_kernel<<<dim3(65536 / 256), blk, 0, stream>>>(out);
}

// Round 2
// 1276.300 us; speedup vs baseline: 5.6556x; 5.6556x over previous
//
#include <hip/hip_runtime.h>
#include <math.h>

// LieNet round 2: bf16 MFMA GEMMs (m97-style 128x128 tile, BK=32,
// global_load_lds width-16 staging, 16x16x32 bf16 MFMA).
//
// h = gelu(src @ map_w^T + map_b)                  (fp32 src staged->bf16)
// blacket(a,b) = gelu([a|b] @ bl_w^T + bl_b)       (K=512, A-source switches at k=256)
// delta = x + blacket(x, h), x = h shifted -256 rows (zero-fill)
// J = blacket(a,bc)+blacket(b,ca)+blacket(c,ab) accumulated into out[512:]
// out = cumsum over S.
//
// Fragment layouts (HW-verified m89/m91): A/B operand: idx=lane&15, k=quad*8+j;
// C/D: col=lane&15, row=quad*4+reg.

typedef unsigned short u16;
typedef __attribute__((ext_vector_type(8))) short short8;
typedef __attribute__((ext_vector_type(4))) float floatx4;

#define DD 256
#define BM 128
#define BN 128
#define BK 32

__device__ __forceinline__ float gelu_exact(float v) {
    return 0.5f * v * (1.0f + erff(v * 0.70710678118654752440f));
}
__device__ __forceinline__ u16 bf_bits(float f) {
    __bf16 b = (__bf16)f;                       // RNE convert
    return __builtin_bit_cast(unsigned short, b);
}
__device__ __forceinline__ float bf2f(u16 u) {
    unsigned int x = ((unsigned int)u) << 16;
    return __builtin_bit_cast(float, x);
}

// Stage a [128 x 32] bf16 tile of X (row stride ldx elems) into lds[128][32].
// Rows gr outside [0,xrows) are zero-filled (slow path only).
__device__ __forceinline__ void stage_bf16(const u16* __restrict__ X, int ldx,
                                           int base_row, int xrows, int k0,
                                           u16* lds, int tid, bool fast)
{
    const int w = tid >> 6, lane = tid & 63;
    if (fast) {
        #pragma unroll
        for (int i = 0; i < 2; ++i) {
            const int row = w * 32 + i * 16 + (lane >> 2);
            const long g = (long)(base_row + row) * ldx + k0 + (lane & 3) * 8;
            u16* ldst = lds + (w * 32 + i * 16) * 32;   // wave-uniform base; lane writes +lane*16B
            __builtin_amdgcn_global_load_lds(
                (const __attribute__((address_space(1))) unsigned int*)(X + g),
                (__attribute__((address_space(3))) unsigned int*)(ldst), 16, 0, 0);
        }
    } else {
        #pragma unroll
        for (int i = 0; i < 2; ++i) {
            const int row = w * 32 + i * 16 + (lane >> 2);
            const int gr = base_row + row;
            short8 v = {0, 0, 0, 0, 0, 0, 0, 0};
            if (gr >= 0 && gr < xrows)
                v = *(const short8*)(X + (long)gr * ldx + k0 + (lane & 3) * 8);
            *(short8*)&lds[row * 32 + (lane & 3) * 8] = v;
        }
    }
}

// fp32 source variant (h projection): load float4 x2, convert to bf16 in regs.
__device__ __forceinline__ void stage_f32(const float* __restrict__ X,
                                          int base_row, int k0, u16* lds, int tid)
{
    const int w = tid >> 6, lane = tid & 63;
    #pragma unroll
    for (int i = 0; i < 2; ++i) {
        const int row = w * 32 + i * 16 + (lane >> 2);
        const long g = (long)(base_row + row) * DD + k0 + (lane & 3) * 8;
        floatx4 f0 = *(const floatx4*)(X + g);
        floatx4 f1 = *(const floatx4*)(X + g + 4);
        short8 v;
        #pragma unroll
        for (int e = 0; e < 4; ++e) {
            v[e]     = (short)bf_bits(f0[e]);
            v[e + 4] = (short)bf_bits(f1[e]);
        }
        *(short8*)&lds[row * 32 + (lane & 3) * 8] = v;
    }
}

// C[n,j] = act( sum_k Aop(n,k) W[j,k] + bias[j] ), Aop = k<256 ? A1[n+s1] : A2[n+s2]
// MODE 0: store bf16.  MODE 1: store fp32 (g + Xadd[n+sadd, j]).  MODE 2: fp32 +=.
template <int MODE, bool AF32>
__global__ __launch_bounds__(256) void gemm_blk(
    const void* __restrict__ A1v, int s1, int xrows1,
    const u16* __restrict__ A2, int s2, int xrows2,
    const u16* __restrict__ W, int K,
    const float* __restrict__ bias,
    void* __restrict__ Outv,
    const u16* __restrict__ Xadd, int sadd, int addrows)
{
    __shared__ u16 Alds[BM * BK];
    __shared__ u16 Blds[BN * BK];

    const int tid = threadIdx.x;
    const int bm = blockIdx.x * BM;
    const int bn = blockIdx.y * BN;
    const int w = tid >> 6, lane = tid & 63;
    const int quad = lane >> 4, lr = lane & 15;
    const int wm = (w & 1) * 64, wn = (w >> 1) * 64;

    floatx4 acc[4][4];
    {
        floatx4 z = {0.f, 0.f, 0.f, 0.f};
        #pragma unroll
        for (int i = 0; i < 4; ++i)
            #pragma unroll
            for (int j = 0; j < 4; ++j) acc[i][j] = z;
    }

    const u16* A1 = (const u16*)A1v;
    const bool fast1 = !AF32 && (bm + s1 >= 0) && (bm + BM + s1 <= xrows1);
    const bool fast2 = (bm + s2 >= 0) && (bm + BM + s2 <= xrows2);

    for (int k0 = 0; k0 < K; k0 += BK) {
        __syncthreads();
        if (k0 < DD) {
            if (AF32) stage_f32((const float*)A1v, bm + s1, k0, Alds, tid);
            else      stage_bf16(A1, DD, bm + s1, xrows1, k0, Alds, tid, fast1);
        } else {
            stage_bf16(A2, DD, bm + s2, xrows2, k0 - DD, Alds, tid, fast2);
        }
        // W tile: rows [bn, bn+128) of W[256][K], cols [k0, k0+32) — always in range
        #pragma unroll
        for (int i = 0; i < 2; ++i) {
            const int row = w * 32 + i * 16 + (lane >> 2);
            const long g = (long)(bn + row) * K + k0 + (lane & 3) * 8;
            u16* ldst = Blds + (w * 32 + i * 16) * 32;
            __builtin_amdgcn_global_load_lds(
                (const __attribute__((address_space(1))) unsigned int*)(W + g),
                (__attribute__((address_space(3))) unsigned int*)(ldst), 16, 0, 0);
        }
        __syncthreads();

        short8 af[4], bfr[4];
        #pragma unroll
        for (int i = 0; i < 4; ++i)
            af[i] = *(const short8*)&Alds[(wm + i * 16 + lr) * BK + quad * 8];
        #pragma unroll
        for (int j = 0; j < 4; ++j)
            bfr[j] = *(const short8*)&Blds[(wn + j * 16 + lr) * BK + quad * 8];
        #pragma unroll
        for (int i = 0; i < 4; ++i)
            #pragma unroll
            for (int j = 0; j < 4; ++j)
                acc[i][j] = __builtin_amdgcn_mfma_f32_16x16x32_bf16(af[i], bfr[j], acc[i][j], 0, 0, 0);
    }

    #pragma unroll
    for (int j = 0; j < 4; ++j) {
        const int n = bn + wn + j * 16 + lr;
        const float bv = bias[n];
        #pragma unroll
        for (int i = 0; i < 4; ++i) {
            const int m0 = bm + wm + i * 16 + quad * 4;
            #pragma unroll
            for (int r = 0; r < 4; ++r) {
                const float g = gelu_exact(acc[i][j][r] + bv);
                const long off = (long)(m0 + r) * DD + n;
                if (MODE == 0) {
                    ((u16*)Outv)[off] = bf_bits(g);
                } else if (MODE == 1) {
                    const int sr = m0 + r + sadd;
                    const float xv = (sr >= 0 && sr < addrows) ? bf2f(Xadd[(long)sr * DD + n]) : 0.0f;
                    ((float*)Outv)[off] = g + xv;
                } else {
                    ((float*)Outv)[off] += g;
                }
            }
        }
    }
}

// fp32 -> bf16 conversion of map_w (65536) then bl_w (131072) into wbuf.
__global__ __launch_bounds__(256) void conv_w(const float* __restrict__ mw,
                                              const float* __restrict__ bw,
                                              u16* __restrict__ out)
{
    const int i = blockIdx.x * 256 + threadIdx.x;      // 0 .. 196607
    out[i] = (i < 65536) ? bf_bits(mw[i]) : bf_bits(bw[i - 65536]);
}

// In-place cumsum along S: one thread per (b,d), 512 serial steps.
__global__ __launch_bounds__(256) void cumsum_kernel(float* __restrict__ out)
{
    const int idx = blockIdx.x * blockDim.x + threadIdx.x;   // 0 .. 65535
    float acc = 0.0f;
    for (int s = 0; s < 512; ++s) {
        const long off = (long)s * 65536 + idx;
        acc += out[off];
        out[off] = acc;
    }
}

extern "C" void kernel_launch(void* const* d_in, const int* in_sizes, int n_in,
                              void* d_out, int out_size, void* d_ws, size_t ws_size,
                              hipStream_t stream)
{
    const float* src   = (const float*)d_in[0];   // (131072, 256)
    const float* map_w = (const float*)d_in[1];   // (256, 256)
    const float* map_b = (const float*)d_in[2];   // (256,)
    const float* bl_w  = (const float*)d_in[3];   // (256, 512)
    const float* bl_b  = (const float*)d_in[4];   // (256,)
    float* out = (float*)d_out;                   // (131072, 256) fp32

    const int SB = 512 * 256;     // 131072
    const int NJ = 510 * 256;     // 130560
    const int B  = 256;

    u16* h_bf = (u16*)d_ws;                       // SB*256 bf16      = 64.0 MB
    u16* bc   = h_bf + (long)SB * DD;             // NJ*256 bf16      = 63.75 MB
    u16* ca   = bc + (long)NJ * DD;
    u16* ab   = ca + (long)NJ * DD;
    u16* wbuf = ab + (long)NJ * DD;               // 196608 bf16
    u16* wmap = wbuf;                             // map_w bf16 [256][256]
    u16* wbl  = wbuf + 65536;                     // bl_w  bf16 [256][512]

    const dim3 blk(256);
    const dim3 gh(SB / BM, DD / BN);              // 1024 x 2
    const dim3 gj(NJ / BM, DD / BN);              // 1020 x 2
    float* outJ = out + (long)2 * B * DD;

    conv_w<<<dim3(768), blk, 0, stream>>>(map_w, bl_w, wbuf);

    // h = gelu(src @ map_w^T + map_b), stored bf16
    gemm_blk<0, true><<<gh, blk, 0, stream>>>(src, 0, SB, nullptr, 0, SB,
                                              wmap, 256, map_b, h_bf, nullptr, 0, 0);
    // out = x + blacket(x, h), x = h shifted -256 (zero-fill)
    gemm_blk<1, false><<<gh, blk, 0, stream>>>(h_bf, -B, SB, h_bf, 0, SB,
                                               wbl, 512, bl_b, out, h_bf, -B, SB);
    // bc = blacket(b, c) = blacket(h[+256], h[+512])
    gemm_blk<0, false><<<gj, blk, 0, stream>>>(h_bf, B, SB, h_bf, 2 * B, SB,
                                               wbl, 512, bl_b, bc, nullptr, 0, 0);
    // ca = blacket(c, a) = blacket(h[+512], h)
    gemm_blk<0, false><<<gj, blk, 0, stream>>>(h_bf, 2 * B, SB, h_bf, 0, SB,
                                               wbl, 512, bl_b, ca, nullptr, 0, 0);
    // ab = blacket(a, b) = blacket(h, h[+256])
    gemm_blk<0, false><<<gj, blk, 0, stream>>>(h_bf, 0, SB, h_bf, B, SB,
                                               wbl, 512, bl_b, ab, nullptr, 0, 0);
    // out[512:] += blacket(a, bc) ; += blacket(b, ca) ; += blacket(c, ab)
    gemm_blk<2, false><<<gj, blk, 0, stream>>>(h_bf, 0, SB, bc, 0, NJ,
                                               wbl, 512, bl_b, outJ, nullptr, 0, 0);
    gemm_blk<2, false><<<gj, blk, 0, stream>>>(h_bf, B, SB, ca, 0, NJ,
                                               wbl, 512, bl_b, outJ, nullptr, 0, 0);
    gemm_blk<2, false><<<gj, blk, 0, stream>>>(h_bf, 2 * B, SB, ab, 0, NJ,
                                               wbl, 512, bl_b, outJ, nullptr, 0, 0);

    cumsum_kernel<<<dim3(65536 / 256), blk, 0, stream>>>(out);
}

// Round 3
// 925.050 us; speedup vs baseline: 7.8030x; 1.3797x over previous
//
#include <hip/hip_runtime.h>
#include <math.h>

// LieNet round 3: single fused kernel for delta + J.
// Identity used: bc[n-512] = gelu([h[n-256]|h[n]]@W+b) = delta-blacket at row n,
// so each 64-row block computes: D(=bc) -> J1([a|P]) -> P2(ca) -> J2([b|P])
// -> P3(ab) -> J3([c|P]) entirely on-chip (P in LDS), one fp32 store of
// delta+J per row. 6 GEMM phases x (64x256xK=512) per block, 2048 blocks.

typedef unsigned short u16;
typedef __attribute__((ext_vector_type(8))) short short8;
typedef __attribute__((ext_vector_type(4))) float floatx4;

#define DD 256
#define PSTR 264          // P-lds row stride (elems): 528B -> 2-way-free banks

__device__ __forceinline__ float gelu_f(float v) {
    // tanh-form gelu; |err| vs exact erf-gelu ~3e-4, far under bf16 rounding
    float u = 0.7978845608028654f * v * (1.0f + 0.044715f * v * v);
    float e = __expf(2.0f * u);
    float t = 1.0f - 2.0f * __builtin_amdgcn_rcpf(e + 1.0f);
    return 0.5f * v * (1.0f + t);
}
__device__ __forceinline__ u16 bf_bits(float f) {
    __bf16 b = (__bf16)f;
    return __builtin_bit_cast(unsigned short, b);
}
__device__ __forceinline__ float bf2f(u16 u) {
    unsigned int x = ((unsigned int)u) << 16;
    return __builtin_bit_cast(float, x);
}

// ---------------- fused delta+J kernel ----------------
// Tile: 64 rows x 256 cols, 256 threads (4 waves), wave w owns cols [64w,64w+64).
// A/B frag: idx=lane&15, k=quad*8+e. C/D: col(n)=lane&15 path, row=quad*4+r
// (operand order identical to the round-2 kernel, HW-verified).
__global__ __launch_bounds__(256) void fused_kernel(
    const u16* __restrict__ h, const u16* __restrict__ W,   // W bf16 [256][512]
    const float* __restrict__ bias, float* __restrict__ out)
{
    __shared__ u16 Alds[64 * 32];
    __shared__ u16 Wlds[256 * 32];
    __shared__ u16 Plds[64 * PSTR];

    const int tid = threadIdx.x;
    const int w = tid >> 6, lane = tid & 63;
    const int quad = lane >> 4, lr = lane & 15;
    const long m0 = (long)blockIdx.x * 64;
    const bool has_x = (m0 >= 256);
    const bool has_J = (m0 >= 512);
    const int st_row = lane >> 2;             // staging row within 16-row chunk
    const int st_col = (lane & 3) * 8;        // staging col (elems)

    float bias_r[4];
    #pragma unroll
    for (int j = 0; j < 4; ++j) bias_r[j] = bias[w * 64 + j * 16 + lr];

    floatx4 Jacc[4][4];
    floatx4 acc[4][4];

    auto zero_acc = [&](floatx4 (&a)[4][4]) {
        floatx4 z = {0.f, 0.f, 0.f, 0.f};
        #pragma unroll
        for (int i = 0; i < 4; ++i)
            #pragma unroll
            for (int j = 0; j < 4; ++j) a[i][j] = z;
    };

    // One 64x256xK=512 GEMM phase. half0 rows: r0 (zero-filled if zero0);
    // half1: rows r1 from global, or the Plds buffer if fromP.
    auto gemm_phase = [&](long r0, bool zero0, long r1, bool fromP) {
        for (int kt = 0; kt < 16; ++kt) {
            const int k0 = kt * 32;
            __syncthreads();
            if (k0 < 256) {
                if (zero0) {
                    short8 z = {0, 0, 0, 0, 0, 0, 0, 0};
                    *(short8*)&Alds[(w * 16 + st_row) * 32 + st_col] = z;
                } else {
                    const long g = (r0 + w * 16 + st_row) * DD + k0 + st_col;
                    __builtin_amdgcn_global_load_lds(
                        (const __attribute__((address_space(1))) unsigned int*)(h + g),
                        (__attribute__((address_space(3))) unsigned int*)(Alds + w * 16 * 32),
                        16, 0, 0);
                }
            } else if (!fromP) {
                const long g = (r1 + w * 16 + st_row) * DD + (k0 - 256) + st_col;
                __builtin_amdgcn_global_load_lds(
                    (const __attribute__((address_space(1))) unsigned int*)(h + g),
                    (__attribute__((address_space(3))) unsigned int*)(Alds + w * 16 * 32),
                    16, 0, 0);
            }
            #pragma unroll
            for (int i = 0; i < 4; ++i) {
                const long g = (long)(w * 64 + i * 16 + st_row) * 512 + k0 + st_col;
                __builtin_amdgcn_global_load_lds(
                    (const __attribute__((address_space(1))) unsigned int*)(W + g),
                    (__attribute__((address_space(3))) unsigned int*)(Wlds + (w * 64 + i * 16) * 32),
                    16, 0, 0);
            }
            __syncthreads();

            short8 af[4], bfr[4];
            const bool rdP = fromP && (k0 >= 256);
            #pragma unroll
            for (int i = 0; i < 4; ++i) {
                if (rdP) af[i] = *(const short8*)&Plds[(i * 16 + lr) * PSTR + (k0 - 256) + quad * 8];
                else     af[i] = *(const short8*)&Alds[(i * 16 + lr) * 32 + quad * 8];
            }
            #pragma unroll
            for (int j = 0; j < 4; ++j)
                bfr[j] = *(const short8*)&Wlds[(w * 64 + j * 16 + lr) * 32 + quad * 8];
            #pragma unroll
            for (int i = 0; i < 4; ++i)
                #pragma unroll
                for (int j = 0; j < 4; ++j)
                    acc[i][j] = __builtin_amdgcn_mfma_f32_16x16x32_bf16(af[i], bfr[j], acc[i][j], 0, 0, 0);
        }
    };

    auto add_gelu = [&]() {                    // Jacc += gelu(acc + bias)
        #pragma unroll
        for (int j = 0; j < 4; ++j)
            #pragma unroll
            for (int i = 0; i < 4; ++i)
                #pragma unroll
                for (int r = 0; r < 4; ++r)
                    Jacc[i][j][r] += gelu_f(acc[i][j][r] + bias_r[j]);
    };
    auto write_P = [&]() {                     // Plds = bf16(gelu(acc + bias))
        #pragma unroll
        for (int j = 0; j < 4; ++j) {
            const int n = w * 64 + j * 16 + lr;
            #pragma unroll
            for (int i = 0; i < 4; ++i)
                #pragma unroll
                for (int r = 0; r < 4; ++r)
                    Plds[(i * 16 + quad * 4 + r) * PSTR + n] =
                        bf_bits(gelu_f(acc[i][j][r] + bias_r[j]));
        }
    };

    // Phase D: G = gelu([b|c]@W+bias); P=G; Jacc = G + x  (b=x=h[m0-256], c=h[m0])
    zero_acc(acc);
    gemm_phase(m0 - 256, !has_x, m0, false);
    #pragma unroll
    for (int j = 0; j < 4; ++j) {
        const int n = w * 64 + j * 16 + lr;
        #pragma unroll
        for (int i = 0; i < 4; ++i) {
            const int rl = i * 16 + quad * 4;
            #pragma unroll
            for (int r = 0; r < 4; ++r) {
                float g = gelu_f(acc[i][j][r] + bias_r[j]);
                Plds[(rl + r) * PSTR + n] = bf_bits(g);
                float xv = has_x ? bf2f(h[(m0 - 256 + rl + r) * DD + n]) : 0.0f;
                Jacc[i][j][r] = g + xv;
            }
        }
    }

    if (has_J) {
        // J1: += gelu([a | P_bc]@W+bias),  a = h[m0-512]
        zero_acc(acc); gemm_phase(m0 - 512, false, 0, true);  add_gelu();
        // P2: ca = gelu([c | a]@W+bias)
        zero_acc(acc); gemm_phase(m0, false, m0 - 512, false); write_P();
        // J2: += gelu([b | P_ca]@W+bias)
        zero_acc(acc); gemm_phase(m0 - 256, false, 0, true);  add_gelu();
        // P3: ab = gelu([a | b]@W+bias)
        zero_acc(acc); gemm_phase(m0 - 512, false, m0 - 256, false); write_P();
        // J3: += gelu([c | P_ab]@W+bias)
        zero_acc(acc); gemm_phase(m0, false, 0, true);        add_gelu();
    }

    #pragma unroll
    for (int j = 0; j < 4; ++j) {
        const int n = w * 64 + j * 16 + lr;
        #pragma unroll
        for (int i = 0; i < 4; ++i) {
            const int rl = i * 16 + quad * 4;
            #pragma unroll
            for (int r = 0; r < 4; ++r)
                out[(m0 + rl + r) * DD + n] = Jacc[i][j][r];
        }
    }
}

// ---------------- h projection (round-2 structure, fp32 src -> bf16 h) ------
__global__ __launch_bounds__(256) void h_gemm(
    const float* __restrict__ src, const u16* __restrict__ Wm,  // Wm [256][256]
    const float* __restrict__ bias, u16* __restrict__ hout)
{
    __shared__ u16 Alds[128 * 32];
    __shared__ u16 Blds[128 * 32];

    const int tid = threadIdx.x;
    const int bm = blockIdx.x * 128;
    const int bn = blockIdx.y * 128;
    const int w = tid >> 6, lane = tid & 63;
    const int quad = lane >> 4, lr = lane & 15;
    const int wm = (w & 1) * 64, wn = (w >> 1) * 64;

    floatx4 acc[4][4];
    {
        floatx4 z = {0.f, 0.f, 0.f, 0.f};
        #pragma unroll
        for (int i = 0; i < 4; ++i)
            #pragma unroll
            for (int j = 0; j < 4; ++j) acc[i][j] = z;
    }

    for (int k0 = 0; k0 < 256; k0 += 32) {
        __syncthreads();
        #pragma unroll
        for (int i = 0; i < 2; ++i) {          // A: fp32 load + convert
            const int row = w * 32 + i * 16 + (lane >> 2);
            const long g = (long)(bm + row) * DD + k0 + (lane & 3) * 8;
            floatx4 f0 = *(const floatx4*)(src + g);
            floatx4 f1 = *(const floatx4*)(src + g + 4);
            short8 v;
            #pragma unroll
            for (int e = 0; e < 4; ++e) {
                v[e]     = (short)bf_bits(f0[e]);
                v[e + 4] = (short)bf_bits(f1[e]);
            }
            *(short8*)&Alds[row * 32 + (lane & 3) * 8] = v;
        }
        #pragma unroll
        for (int i = 0; i < 2; ++i) {          // W tile
            const int row = w * 32 + i * 16 + (lane >> 2);
            const long g = (long)(bn + row) * DD + k0 + (lane & 3) * 8;
            __builtin_amdgcn_global_load_lds(
                (const __attribute__((address_space(1))) unsigned int*)(Wm + g),
                (__attribute__((address_space(3))) unsigned int*)(Blds + (w * 32 + i * 16) * 32),
                16, 0, 0);
        }
        __syncthreads();

        short8 af[4], bfr[4];
        #pragma unroll
        for (int i = 0; i < 4; ++i)
            af[i] = *(const short8*)&Alds[(wm + i * 16 + lr) * 32 + quad * 8];
        #pragma unroll
        for (int j = 0; j < 4; ++j)
            bfr[j] = *(const short8*)&Blds[(wn + j * 16 + lr) * 32 + quad * 8];
        #pragma unroll
        for (int i = 0; i < 4; ++i)
            #pragma unroll
            for (int j = 0; j < 4; ++j)
                acc[i][j] = __builtin_amdgcn_mfma_f32_16x16x32_bf16(af[i], bfr[j], acc[i][j], 0, 0, 0);
    }

    #pragma unroll
    for (int j = 0; j < 4; ++j) {
        const int n = bn + wn + j * 16 + lr;
        const float bv = bias[n];
        #pragma unroll
        for (int i = 0; i < 4; ++i) {
            const int m = bm + wm + i * 16 + quad * 4;
            #pragma unroll
            for (int r = 0; r < 4; ++r)
                hout[(long)(m + r) * DD + n] = bf_bits(gelu_f(acc[i][j][r] + bv));
        }
    }
}

// fp32 -> bf16 of map_w (65536) then bl_w (131072)
__global__ __launch_bounds__(256) void conv_w(const float* __restrict__ mw,
                                              const float* __restrict__ bw,
                                              u16* __restrict__ outw)
{
    const int i = blockIdx.x * 256 + threadIdx.x;
    outw[i] = (i < 65536) ? bf_bits(mw[i]) : bf_bits(bw[i - 65536]);
}

__global__ __launch_bounds__(256) void cumsum_kernel(float* __restrict__ out)
{
    const int idx = blockIdx.x * blockDim.x + threadIdx.x;   // 0..65535
    float acc = 0.0f;
    for (int s = 0; s < 512; ++s) {
        const long off = (long)s * 65536 + idx;
        acc += out[off];
        out[off] = acc;
    }
}

extern "C" void kernel_launch(void* const* d_in, const int* in_sizes, int n_in,
                              void* d_out, int out_size, void* d_ws, size_t ws_size,
                              hipStream_t stream)
{
    const float* src   = (const float*)d_in[0];
    const float* map_w = (const float*)d_in[1];
    const float* map_b = (const float*)d_in[2];
    const float* bl_w  = (const float*)d_in[3];
    const float* bl_b  = (const float*)d_in[4];
    float* out = (float*)d_out;

    const int SB = 512 * 256;                 // 131072 rows

    u16* h_bf = (u16*)d_ws;                   // 64 MB
    u16* wbuf = h_bf + (long)SB * DD;         // 196608 u16
    u16* wmap = wbuf;
    u16* wbl  = wbuf + 65536;

    const dim3 blk(256);

    conv_w<<<dim3(768), blk, 0, stream>>>(map_w, bl_w, wbuf);
    h_gemm<<<dim3(SB / 128, 2), blk, 0, stream>>>(src, wmap, map_b, h_bf);
    fused_kernel<<<dim3(SB / 64), blk, 0, stream>>>(h_bf, wbl, bl_b, out);
    cumsum_kernel<<<dim3(65536 / 256), blk, 0, stream>>>(out);
}